// Round 1
// baseline (527.532 us; speedup 1.0000x reference)
//
#include <hip/hip_runtime.h>

typedef unsigned short u16;
typedef short v8s __attribute__((ext_vector_type(8)));
typedef float v4f __attribute__((ext_vector_type(4)));

// ---- problem constants ----
#define KDIM 768
#define M_TEXT 1536            // 32*48
#define N_VOCAB 30522
#define N_VOCAB_PAD 30592      // 239*128
#define M_HC 1056              // 32*33
#define M_HC_PAD 1152          // 9*128
#define N_IOU 2304             // 3*768
#define OUT_IOU_OFF 46881792
#define OUT_MASK_OFF 46983168

__device__ __forceinline__ u16 f2bf(float f) {
  unsigned u = __float_as_uint(f);
  u += 0x7fffu + ((u >> 16) & 1u);   // RNE
  return (u16)(u >> 16);
}

// ---------------- prep: convert activations to bf16 (hc padded to 1152 rows) -------------
__global__ __launch_bounds__(256) void prep_cvt(const float* __restrict__ xt_in,
                                                const float* __restrict__ hc_in,
                                                u16* __restrict__ xt,
                                                u16* __restrict__ hcb) {
  const int NXT = M_TEXT * KDIM / 4;      // 294912 float4s
  int i = blockIdx.x * 256 + threadIdx.x; // grid sized exactly (294912+221184)/256
  if (i < NXT) {
    float4 v = ((const float4*)xt_in)[i];
    ushort4 o; o.x = f2bf(v.x); o.y = f2bf(v.y); o.z = f2bf(v.z); o.w = f2bf(v.w);
    ((ushort4*)xt)[i] = o;
  } else {
    int j = i - NXT;                      // < 1152*192
    int row = j / 192;
    float4 v = make_float4(0.f, 0.f, 0.f, 0.f);
    if (row < M_HC) v = ((const float4*)hc_in)[j];
    ushort4 o; o.x = f2bf(v.x); o.y = f2bf(v.y); o.z = f2bf(v.z); o.w = f2bf(v.w);
    ((ushort4*)hcb)[j] = o;
  }
}

// ---------------- transpose + convert: in fp32 (768 x C) -> out bf16 (Cpad x 768) --------
// grid: (768/64, Cpad/64, batch). Rows >= C are zero-filled (w_t2 pad).
__global__ __launch_bounds__(256) void transpose_cvt(const float* __restrict__ in,
                                                     u16* __restrict__ out,
                                                     int C, long inBatch, long outBatch) {
  __shared__ float tile[64][65];
  const float* ip = in + (long)blockIdx.z * inBatch;
  u16* op = out + (long)blockIdx.z * outBatch;
  int r0 = blockIdx.x * 64, c0 = blockIdx.y * 64;
  int tx = threadIdx.x & 63, tg = threadIdx.x >> 6;
#pragma unroll
  for (int i = 0; i < 16; ++i) {
    int r = tg + i * 4;
    int gc = c0 + tx;
    tile[r][tx] = (gc < C) ? ip[(long)(r0 + r) * C + gc] : 0.f;
  }
  __syncthreads();
#pragma unroll
  for (int i = 0; i < 16; ++i) {
    int cc = tg + i * 4;
    op[(long)(c0 + cc) * KDIM + r0 + tx] = f2bf(tile[tx][cc]);
  }
}

// ---------------- mask map ----------------
__global__ void mask_kernel(float* __restrict__ out) {
  int idx = blockIdx.x * 256 + threadIdx.x;
  if (idx >= 1056) return;
  int i = idx / 33, j = idx % 33;
  float v = 0.f;
  int hi = min(i + 17, 33);
  if (j >= i + 1 && j < hi) v = 1.f;
  if ((i & 1) == 0 && i < 16 && j >= 18 + i && ((j - (18 + i)) & 1) == 0) v = 1.f;
  out[OUT_MASK_OFF + idx] = v;
}

// ---------------- m97-style GEMM: C[M,N] = A[M,768] * BT[N,768]^T ----------------
// MODE 0: fout = acc + bias[c], guard c < nmax (ldc = nmax)
// MODE 1: bfout = bf16(relu(acc + bias[c])), ldc
// MODE 2: fout = acc (no bias, no guard), ldc
template <int MODE>
__global__ __launch_bounds__(256)
void gemm_bt(const u16* __restrict__ A, const u16* __restrict__ BT,
             float* __restrict__ fout, u16* __restrict__ bfout,
             const float* __restrict__ bias, int ldc, int nmax) {
  __shared__ u16 sA[128 * 32];
  __shared__ u16 sB[128 * 32];
  const int tid = threadIdx.x;
  const int wid = tid >> 6;
  const int lane = tid & 63;
  const int lrow = lane & 15;
  const int quad = lane >> 4;
  const int wm = (wid & 1) * 64;
  const int wn = (wid >> 1) * 64;
  const int m0 = blockIdx.y * 128;
  const int n0 = blockIdx.x * 128;

  // staging: each wave stages 32 rows of A-tile and 32 rows of B-tile (2 insts each)
  const int srow = wid * 32 + (lane >> 2);
  const int scol = (lane & 3) * 8;
  const u16* gA = A + (long)(m0 + srow) * KDIM + scol;
  const u16* gB = BT + (long)(n0 + srow) * KDIM + scol;
  u16* lA = &sA[(wid * 32) * 32];
  u16* lB = &sB[(wid * 32) * 32];

  v4f acc[4][4];
#pragma unroll
  for (int i = 0; i < 4; ++i)
#pragma unroll
    for (int j = 0; j < 4; ++j) acc[i][j] = (v4f){0.f, 0.f, 0.f, 0.f};

  const v8s* pA = (const v8s*)sA;
  const v8s* pB = (const v8s*)sB;
  const int ia0 = (wm + lrow) * 4 + quad;
  const int ib0 = (wn + lrow) * 4 + quad;

  for (int kt = 0; kt < KDIM / 32; ++kt) {
    const u16* ga = gA + kt * 32;
    const u16* gb = gB + kt * 32;
    __builtin_amdgcn_global_load_lds((const __attribute__((address_space(1))) void*)ga,
                                     (__attribute__((address_space(3))) void*)lA, 16, 0, 0);
    __builtin_amdgcn_global_load_lds((const __attribute__((address_space(1))) void*)(ga + 16 * KDIM),
                                     (__attribute__((address_space(3))) void*)(lA + 16 * 32), 16, 0, 0);
    __builtin_amdgcn_global_load_lds((const __attribute__((address_space(1))) void*)gb,
                                     (__attribute__((address_space(3))) void*)lB, 16, 0, 0);
    __builtin_amdgcn_global_load_lds((const __attribute__((address_space(1))) void*)(gb + 16 * KDIM),
                                     (__attribute__((address_space(3))) void*)(lB + 16 * 32), 16, 0, 0);
    __syncthreads();

    v8s af[4], bfr[4];
#pragma unroll
    for (int mt = 0; mt < 4; ++mt) af[mt] = pA[ia0 + mt * 64];
#pragma unroll
    for (int nt = 0; nt < 4; ++nt) bfr[nt] = pB[ib0 + nt * 64];
#pragma unroll
    for (int mt = 0; mt < 4; ++mt)
#pragma unroll
      for (int nt = 0; nt < 4; ++nt)
        acc[mt][nt] = __builtin_amdgcn_mfma_f32_16x16x32_bf16(af[mt], bfr[nt], acc[mt][nt], 0, 0, 0);
    __syncthreads();
  }

  // epilogue: C/D layout col = lane&15, row = quad*4 + reg  [verified m89/m91]
#pragma unroll
  for (int nt = 0; nt < 4; ++nt) {
    int c = n0 + wn + nt * 16 + lrow;
    float bv = 0.f;
    if (MODE == 0) { if (c < nmax) bv = bias[c]; }
    if (MODE == 1) bv = bias[c];
#pragma unroll
    for (int mt = 0; mt < 4; ++mt) {
#pragma unroll
      for (int r = 0; r < 4; ++r) {
        int row = m0 + wm + mt * 16 + quad * 4 + r;
        float v = acc[mt][nt][r] + bv;
        if (MODE == 0) {
          if (c < nmax) fout[(long)row * ldc + c] = v;
        } else if (MODE == 1) {
          bfout[(long)row * ldc + c] = f2bf(fmaxf(v, 0.f));
        } else {
          fout[(long)row * ldc + c] = v;
        }
      }
    }
  }
}

// ---------------- IOU combine: one wave per (b,s,t) ----------------
__global__ __launch_bounds__(256) void iou_combine(const float* __restrict__ Xcat,
                                                   const float* __restrict__ b1,
                                                   const float* __restrict__ w2,
                                                   const float* __restrict__ b2,
                                                   float* __restrict__ out) {
  int gw = (blockIdx.x * 256 + threadIdx.x) >> 6;
  int lane = threadIdx.x & 63;
  if (gw >= 32 * 32 * 33) return;
  int b = gw / 1056;
  int rem = gw % 1056;
  int s = rem / 33;
  int t = rem % 33;
  int cidx = (s + t) >> 1;
  const float* ps = Xcat + (long)(b * 33 + s) * N_IOU;
  const float* pc = Xcat + (long)(b * 33 + cidx) * N_IOU + 768;
  const float* pe = Xcat + (long)(b * 33 + t) * N_IOU + 1536;
  float a0 = 0.f, a1 = 0.f, a2 = 0.f;
#pragma unroll
  for (int j = 0; j < 3; ++j) {
    int h0 = j * 256 + lane * 4;
    float4 vs = *(const float4*)(ps + h0);
    float4 vc = *(const float4*)(pc + h0);
    float4 ve = *(const float4*)(pe + h0);
    float4 vb = *(const float4*)(b1 + h0);
    const float* fs = (const float*)&vs;
    const float* fc = (const float*)&vc;
    const float* fe = (const float*)&ve;
    const float* fb = (const float*)&vb;
#pragma unroll
    for (int c = 0; c < 4; ++c) {
      float v = fmaxf(fs[c] + fc[c] + fe[c] + fb[c], 0.f);
      int h = h0 + c;
      a0 += v * w2[h * 3 + 0];
      a1 += v * w2[h * 3 + 1];
      a2 += v * w2[h * 3 + 2];
    }
  }
#pragma unroll
  for (int off = 32; off > 0; off >>= 1) {
    a0 += __shfl_down(a0, off, 64);
    a1 += __shfl_down(a1, off, 64);
    a2 += __shfl_down(a2, off, 64);
  }
  if (lane == 0) {
    int base = OUT_IOU_OFF + b * 3168 + s * 33 + t;   // ((b*3+k)*32+s)*33+t
    out[base + 0 * 1056] = a0 + b2[0];
    out[base + 1 * 1056] = a1 + b2[1];
    out[base + 2 * 1056] = a2 + b2[2];
  }
}

extern "C" void kernel_launch(void* const* d_in, const int* in_sizes, int n_in,
                              void* d_out, int out_size, void* d_ws, size_t ws_size,
                              hipStream_t stream) {
  const float* hst  = (const float*)d_in[0];  // (32,48,768)
  const float* hso  = (const float*)d_in[1];  // (32,33,768)
  const float* w_t1 = (const float*)d_in[2];  // (768,768)
  const float* b_t1 = (const float*)d_in[3];  // (768,)
  const float* w_t2 = (const float*)d_in[4];  // (768,30522)
  const float* b_t2 = (const float*)d_in[5];  // (30522,)
  const float* w_i1 = (const float*)d_in[6];  // (2304,768)
  const float* b_i1 = (const float*)d_in[7];  // (768,)
  const float* w_i2 = (const float*)d_in[8];  // (768,3)
  const float* b_i2 = (const float*)d_in[9];  // (3,)
  float* out = (float*)d_out;

  // workspace layout (bytes)
  char* ws = (char*)d_ws;
  u16*   w_t2T = (u16*)(ws + 0);           // 30592*768*2 = 46,989,312
  u16*   xt    = (u16*)(ws + 46989312);    //  1536*768*2 =  2,359,296
  u16*   w_t1T = (u16*)(ws + 49348608);    //   768*768*2 =  1,179,648
  u16*   htext = (u16*)(ws + 50528256);    //  1536*768*2 =  2,359,296
  u16*   hcb   = (u16*)(ws + 52887552);    //  1152*768*2 =  1,769,472
  u16*   w_i1T = (u16*)(ws + 54657024);    //  2304*768*2 =  3,538,944
  float* Xcat  = (float*)(ws + 58195968);  // 1152*2304*4 = 10,616,832  (end 68,812,800)

  // 1) conversions / transposes / mask
  prep_cvt<<<dim3(2016), dim3(256), 0, stream>>>(hst, hso, xt, hcb);
  transpose_cvt<<<dim3(12, 12, 1), dim3(256), 0, stream>>>(w_t1, w_t1T, 768, 0, 0);
  transpose_cvt<<<dim3(12, N_VOCAB_PAD / 64, 1), dim3(256), 0, stream>>>(w_t2, w_t2T, N_VOCAB, 0, 0);
  transpose_cvt<<<dim3(12, 12, 3), dim3(256), 0, stream>>>(w_i1, w_i1T, 768, 768L * 768, 768L * 768);
  mask_kernel<<<dim3(5), dim3(256), 0, stream>>>(out);

  // 2) text path
  gemm_bt<1><<<dim3(KDIM / 128, M_TEXT / 128), dim3(256), 0, stream>>>(
      xt, w_t1T, nullptr, htext, b_t1, KDIM, KDIM);
  gemm_bt<0><<<dim3(N_VOCAB_PAD / 128, M_TEXT / 128), dim3(256), 0, stream>>>(
      htext, w_t2T, out, nullptr, b_t2, N_VOCAB, N_VOCAB);

  // 3) iou path
  gemm_bt<2><<<dim3(N_IOU / 128, M_HC_PAD / 128), dim3(256), 0, stream>>>(
      hcb, w_i1T, Xcat, nullptr, nullptr, N_IOU, N_IOU);
  iou_combine<<<dim3(8448), dim3(256), 0, stream>>>(Xcat, b_i1, w_i2, b_i2, out);
}